// Round 6
// baseline (34877.316 us; speedup 1.0000x reference)
//
#include <hip/hip_runtime.h>
#include <hip/hip_bf16.h>

// Decoder: 128-step GRU + Luong attention, B=64, H=1024. Persistent kernel,
// 256 WGs x 1024 thr (16 waves/CU, 4/SIMD), 2-level grid barrier, 5 phases.
// NUMERICS (frozen): 3-way bf16 splits + 6-pass MFMA; fp32 state; fp32 o_enc
// attention; sparse value (skip w<1e-8). Score/softmax/value trees identical
// to round 5 (passed 0.0117).
// ROUND 6: concurrency attack (round-5 lesson: 712 GB/s miss-path, latency-
// bound). 4 waves/SIMD; XCD-local PH3 (b=wg&63 -> 4 collab WGs on one XCD);
// PH2 idle waves prefetch this WG's score rows into its XCD L2.

#define NWG 256
#define NTHR 1024
constexpr int BB = 64, TD = 128, TE = 256, HH = 1024, H3 = 3072;

typedef __attribute__((ext_vector_type(8))) __bf16 bf16x8;
typedef __attribute__((ext_vector_type(4))) float f32x4;
using bf = __hip_bfloat16;

__device__ __forceinline__ f32x4 mfma16(bf16x8 a, bf16x8 b, f32x4 c) {
  return __builtin_amdgcn_mfma_f32_16x16x32_bf16(a, b, c, 0, 0, 0);
}

struct Args {
  const float *x, *o_enc, *bfeed, *bxi, *bhr, *batt;
  const bf *Wf0, *Wf1, *Wf2, *Wh0, *Wh1, *Wh2;
  const bf *WxF0, *WxF1, *WxF2, *WxX0, *WxX1, *WxX2, *Wa0, *Wa1, *Wa2;
  float *h_f32;  // 2 planes ping-pong
  float *gxp;    // PH2: 4 planes 64x3072; PH4: 16 planes 64x1024 (1M floats)
  float *gh, *scores;
  bf *hs0, *hs1, *hs2, *ff0, *ff1, *ff2, *ifd0, *ifd1, *ifd2;
  bf *xt0, *xt1, *xt2, *vl0, *vl1, *vl2;
  unsigned *cnt, *cnt2, *go, *afl;
  float *out;
};

__device__ __forceinline__ void gbar(unsigned ep, const Args& a, int wg) {
  __syncthreads();
  if (threadIdx.x == 0) {
    __threadfence();
    unsigned* sub = a.cnt + (wg & 15) * 32;
    unsigned o = __hip_atomic_fetch_add(sub, 1u, __ATOMIC_ACQ_REL, __HIP_MEMORY_SCOPE_AGENT);
    if (o == 15) {
      __hip_atomic_store(sub, 0u, __ATOMIC_RELAXED, __HIP_MEMORY_SCOPE_AGENT);
      unsigned o2 = __hip_atomic_fetch_add(a.cnt2, 1u, __ATOMIC_ACQ_REL, __HIP_MEMORY_SCOPE_AGENT);
      if (o2 == 15) {
        __hip_atomic_store(a.cnt2, 0u, __ATOMIC_RELAXED, __HIP_MEMORY_SCOPE_AGENT);
        __hip_atomic_store(a.go, ep, __ATOMIC_RELEASE, __HIP_MEMORY_SCOPE_AGENT);
      }
    }
    while (__hip_atomic_load(a.go, __ATOMIC_RELAXED, __HIP_MEMORY_SCOPE_AGENT) < ep)
      __builtin_amdgcn_s_sleep(2);
    __threadfence();
  }
  __syncthreads();
}

__device__ __forceinline__ void split3_write(bf* p0, bf* p1, bf* p2, size_t i, float v) {
  bf b0 = __float2bfloat16(v);
  float r1 = v - __bfloat162float(b0);
  bf b1 = __float2bfloat16(r1);
  float r2 = r1 - __bfloat162float(b1);
  p0[i] = b0; p1[i] = b1; p2[i] = __float2bfloat16(r2);
}

template <int K>
__device__ __forceinline__ f32x4 gemm6(const bf* A0, const bf* A1, const bf* A2,
                                       const bf* B0, const bf* B1, const bf* B2) {
  f32x4 c0 = {0.f, 0.f, 0.f, 0.f}, c1 = c0, c2 = c0, c3 = c0;
#pragma unroll 4
  for (int k = 0; k < K; k += 32) {
    bf16x8 a0 = *(const bf16x8*)(A0 + k);
    bf16x8 a1 = *(const bf16x8*)(A1 + k);
    bf16x8 a2 = *(const bf16x8*)(A2 + k);
    bf16x8 b0 = *(const bf16x8*)(B0 + k);
    bf16x8 b1 = *(const bf16x8*)(B1 + k);
    bf16x8 b2 = *(const bf16x8*)(B2 + k);
    c0 = mfma16(a0, b0, c0);
    c1 = mfma16(a0, b1, c1);
    c2 = mfma16(a1, b0, c2);
    c3 = mfma16(a1, b1, c3);
    c0 = mfma16(a0, b2, c0);
    c1 = mfma16(a2, b0, c1);
  }
  f32x4 s;
#pragma unroll
  for (int i = 0; i < 4; ++i) s[i] = (c0[i] + c1[i]) + (c2[i] + c3[i]);
  return s;
}

__global__ __launch_bounds__(NTHR, 4) void decoder_main(Args a) {
  const int wg = blockIdx.x;
  const int tid = threadIdx.x;
  const int lane = tid & 63;
  const int wv = tid >> 6;       // wave 0..15
  const int lrow = lane & 15;
  const int lkg = lane >> 4;

  __shared__ float s_acc[4][4][16][16];  // PH1: [K-quarter][M-tile][16][16]
  __shared__ float s_h[HH];
  __shared__ float s_sm[TE];
  __shared__ float s_red[8];
  __shared__ float s_val[2][256];

  unsigned ep = 0;

  for (int t = 0; t < TD; ++t) {
    // ===== PH1: ffeed (WGs 0..63) / gh (WGs 64..255); waves = (mt, kq) =====
    {
      const bool isf = (wg < 64);
      const int j0 = (isf ? wg : wg - 64) * 16;
      const bf* A0 = isf ? a.ifd0 : a.hs0;
      const bf* A1 = isf ? a.ifd1 : a.hs1;
      const bf* A2 = isf ? a.ifd2 : a.hs2;
      const bf* B0 = isf ? a.Wf0 : a.Wh0;
      const bf* B1 = isf ? a.Wf1 : a.Wh1;
      const bf* B2 = isf ? a.Wf2 : a.Wh2;
      const int mt = wv >> 2, kq = wv & 3;
      const size_t aoff = (size_t)(mt * 16 + lrow) * HH + kq * 256 + lkg * 8;
      const size_t boff = (size_t)(j0 + lrow) * HH + kq * 256 + lkg * 8;
      f32x4 acc = gemm6<256>(A0 + aoff, A1 + aoff, A2 + aoff, B0 + boff, B1 + boff, B2 + boff);
#pragma unroll
      for (int r = 0; r < 4; ++r) s_acc[kq][mt][lkg * 4 + r][lrow] = acc[r];
      __syncthreads();
      {
        const int row = tid >> 4, c = tid & 15;   // 1024 outputs, 1 per thread
        const int emt = row >> 4, r2 = row & 15;
        float v = (s_acc[0][emt][r2][c] + s_acc[1][emt][r2][c]) +
                  (s_acc[2][emt][r2][c] + s_acc[3][emt][r2][c]);
        const int col = j0 + c;
        if (isf) {
          float f = tanhf(v + a.bfeed[col]);
          split3_write(a.ff0, a.ff1, a.ff2, (size_t)row * HH + col, f);
        } else {
          a.gh[(size_t)row * H3 + col] = v + a.bhr[col];
        }
      }
    }
    gbar(++ep, a, wg);

    // ===== PH2: gx partials; 3072 wave-units (kq2,kh2,jt,g,mt) K=512 each;
    //            waves 12..15 prefetch this WG's PH3 score rows into L2 =====
    if (wv < 12) {
      const int unit = wg * 12 + wv;
      const int kq2 = unit & 1;            // K-half within operand
      const int kh2 = (unit >> 1) & 1;     // 0: ff operand, 1: xt operand
      const int jt = (unit >> 2) & 63;
      const int gm = unit >> 8;            // 0..11
      const int g = gm >> 2, mt = gm & 3;
      const bf* A0 = kh2 ? a.xt0 : a.ff0;
      const bf* A1 = kh2 ? a.xt1 : a.ff1;
      const bf* A2 = kh2 ? a.xt2 : a.ff2;
      const bf* B0 = kh2 ? a.WxX0 : a.WxF0;
      const bf* B1 = kh2 ? a.WxX1 : a.WxF1;
      const bf* B2 = kh2 ? a.WxX2 : a.WxF2;
      const size_t aoff = (size_t)(mt * 16 + lrow) * HH + kq2 * 512 + lkg * 8;
      const size_t boff = (size_t)(g * HH + jt * 16 + lrow) * HH + kq2 * 512 + lkg * 8;
      f32x4 acc = gemm6<512>(A0 + aoff, A1 + aoff, A2 + aoff, B0 + boff, B1 + boff, B2 + boff);
      const int p = kh2 * 2 + kq2;
      const int gcol = g * 1024 + jt * 16 + lrow;
#pragma unroll
      for (int r = 0; r < 4; ++r)
        a.gxp[(size_t)(p * 64 + mt * 16 + lkg * 4 + r) * H3 + gcol] = acc[r];
    } else {
      // prefetch o_enc rows [b, q*64 .. q*64+63] into this XCD's L2
      const int b3 = wg & 63, q3 = wg >> 6;
      const int pw = wv - 12;  // 0..3, 16 rows each
      const float* pbase = a.o_enc + ((size_t)b3 * TE + q3 * 64 + pw * 16) * HH + lane * 4;
      float pf = 0.f;
      for (int rr = 0; rr < 16; ++rr) {
        const float* prow = pbase + (size_t)rr * HH;
        f32x4 v0 = *(const f32x4*)(prow);
        f32x4 v1 = *(const f32x4*)(prow + 256);
        f32x4 v2 = *(const f32x4*)(prow + 512);
        f32x4 v3 = *(const f32x4*)(prow + 768);
        pf += v0[0] + v1[0] + v2[0] + v3[0];
      }
      asm volatile("" :: "v"(pf));  // keep loads live (no DCE)
    }
    gbar(++ep, a, wg);

    // ===== PH3: GRU pointwise + scores + softmax + sparse value =====
    // XCD-local remap: b = wg&63, q = wg>>6 -> collab WGs {b,64+b,128+b,192+b}
    // all on XCD b%8; value pass hits L2 lines the score pass fetched.
    {
      const int b = wg & 63, q = wg >> 6;
      const float* hold = a.h_f32 + (size_t)(t & 1) * (BB * HH);
      float* hnew = a.h_f32 + (size_t)((t + 1) & 1) * (BB * HH);
      const float* ghb = a.gh + (size_t)b * H3;
      {
        const int col = tid;  // 1024 cols, 1 per thread
        const float* g0 = a.gxp + (size_t)(0 * 64 + b) * H3;
        const float* g1 = a.gxp + (size_t)(1 * 64 + b) * H3;
        const float* g2 = a.gxp + (size_t)(2 * 64 + b) * H3;
        const float* g3 = a.gxp + (size_t)(3 * 64 + b) * H3;
        float gz = a.bxi[col] + ((g0[col] + g1[col]) + (g2[col] + g3[col]));
        float gr = a.bxi[HH + col] +
                   ((g0[HH + col] + g1[HH + col]) + (g2[HH + col] + g3[HH + col]));
        float gc = a.bxi[2 * HH + col] + ((g0[2 * HH + col] + g1[2 * HH + col]) +
                                          (g2[2 * HH + col] + g3[2 * HH + col]));
        float z = 1.f / (1.f + expf(-(gz + ghb[col])));
        float rr = 1.f / (1.f + expf(-(gr + ghb[HH + col])));
        float hc = tanhf(gc + rr * ghb[2 * HH + col]);
        float hn = z * hold[(size_t)b * HH + col] + (1.f - z) * hc;
        s_h[col] = hn;
        if (q == 0) {
          hnew[(size_t)b * HH + col] = hn;
          split3_write(a.hs0, a.hs1, a.hs2, (size_t)b * HH + col, hn);
        }
      }
      __syncthreads();
      // scores: 16 waves x 4 rows, lane layout identical to round 5
      {
        f32x4 sh0 = *(const f32x4*)(s_h + 0 + lane * 4);
        f32x4 sh1 = *(const f32x4*)(s_h + 256 + lane * 4);
        f32x4 sh2 = *(const f32x4*)(s_h + 512 + lane * 4);
        f32x4 sh3 = *(const f32x4*)(s_h + 768 + lane * 4);
        const float* obase = a.o_enc + ((size_t)b * TE + q * 64 + wv * 4) * HH + lane * 4;
#pragma unroll 2
        for (int i = 0; i < 4; ++i) {
          const float* orow = obase + (size_t)i * HH;
          f32x4 o0 = *(const f32x4*)(orow);
          f32x4 o1 = *(const f32x4*)(orow + 256);
          f32x4 o2 = *(const f32x4*)(orow + 512);
          f32x4 o3 = *(const f32x4*)(orow + 768);
          float s = o0[0] * sh0[0] + o0[1] * sh0[1] + o0[2] * sh0[2] + o0[3] * sh0[3]
                  + o1[0] * sh1[0] + o1[1] * sh1[1] + o1[2] * sh1[2] + o1[3] * sh1[3]
                  + o2[0] * sh2[0] + o2[1] * sh2[1] + o2[2] * sh2[2] + o2[3] * sh2[3]
                  + o3[0] * sh3[0] + o3[1] * sh3[1] + o3[2] * sh3[2] + o3[3] * sh3[3];
          for (int off = 32; off; off >>= 1) s += __shfl_xor(s, off);
          if (lane == 0) a.scores[(size_t)b * TE + q * 64 + wv * 4 + i] = s;
        }
      }
      __syncthreads();
      if (tid == 0) {
        __threadfence();
        __hip_atomic_store(&a.afl[b * 4 + q], (unsigned)(t + 1),
                           __ATOMIC_RELEASE, __HIP_MEMORY_SCOPE_AGENT);
        for (int p = 1; p < 4; ++p) {
          unsigned idx = b * 4 + ((q + p) & 3);
          while (__hip_atomic_load(&a.afl[idx], __ATOMIC_RELAXED, __HIP_MEMORY_SCOPE_AGENT)
                 < (unsigned)(t + 1))
            __builtin_amdgcn_s_sleep(1);
        }
        __threadfence();
      }
      __syncthreads();
      // softmax over 256 (first 4 waves), tree identical to round 5
      float sc = 0.f, p = 0.f;
      if (tid < 256) {
        sc = a.scores[(size_t)b * TE + tid];
        float v = sc;
        for (int off = 32; off; off >>= 1) v = fmaxf(v, __shfl_xor(v, off));
        if (lane == 0) s_red[wv] = v;
      }
      __syncthreads();
      {
        float mx = fmaxf(fmaxf(s_red[0], s_red[1]), fmaxf(s_red[2], s_red[3]));
        if (tid < 256) {
          p = expf(sc - mx);
          float sum = p;
          for (int off = 32; off; off >>= 1) sum += __shfl_xor(sum, off);
          if (lane == 0) s_red[4 + wv] = sum;
        }
      }
      __syncthreads();
      if (tid < 256) {
        float tot = s_red[4] + s_red[5] + s_red[6] + s_red[7];
        s_sm[tid] = p / tot;
      }
      __syncthreads();
      // sparse value: tree identical to round 5 (2-way t-split, 512 threads)
      if (tid < 512) {
        const int c = tid & 255, th = tid >> 8;
        const int j = q * 256 + c;
        const float* ob = a.o_enc + (size_t)b * TE * HH + j;
        float accv = 0.f;
        for (int tt2 = th * 128; tt2 < th * 128 + 128; ++tt2) {
          float w2 = s_sm[tt2];
          if (w2 > 1e-8f) accv += w2 * ob[(size_t)tt2 * HH];
        }
        s_val[th][c] = accv;
      }
      __syncthreads();
      if (tid < 256)
        split3_write(a.vl0, a.vl1, a.vl2, (size_t)b * HH + q * 256 + tid,
                     s_val[0][tid] + s_val[1][tid]);
    }
    gbar(++ep, a, wg);

    // ===== PH4: att partials; 4096 units: WG=(mt,cu), wave=kq16 (K=128) =====
    {
      const int cu = wg & 63;
      const int mt = wg >> 6;
      const int kq16 = wv;
      const bool isv = (kq16 < 8);
      const int koff = (kq16 & 7) * 128;
      const bf* A0 = isv ? a.vl0 : a.hs0;
      const bf* A1 = isv ? a.vl1 : a.hs1;
      const bf* A2 = isv ? a.vl2 : a.hs2;
      const size_t aoff = (size_t)(mt * 16 + lrow) * HH + koff + lkg * 8;
      const size_t boff = (size_t)(cu * 16 + lrow) * 2048 + kq16 * 128 + lkg * 8;
      f32x4 acc = gemm6<128>(A0 + aoff, A1 + aoff, A2 + aoff,
                             a.Wa0 + boff, a.Wa1 + boff, a.Wa2 + boff);
#pragma unroll
      for (int r = 0; r < 4; ++r)
        a.gxp[(size_t)(kq16 * 64 + mt * 16 + lkg * 4 + r) * 1024 + cu * 16 + lrow] = acc[r];
    }
    gbar(++ep, a, wg);

    // ===== PH5: att reduce + tanh -> out/ifd; stage x_{t+1} =====
    {
      const int id = wg * NTHR + tid;  // 0..262143
      if (id < 65536) {
        const int row = id >> 10, col = id & 1023;
        float s = a.batt[col];
#pragma unroll
        for (int kq = 0; kq < 16; ++kq) s += a.gxp[(size_t)(kq * 64 + row) * 1024 + col];
        float hv = tanhf(s);
        a.out[((size_t)row * TD + t) * HH + col] = hv;
        split3_write(a.ifd0, a.ifd1, a.ifd2, (size_t)row * HH + col, hv);
      } else if (id < 131072 && t + 1 < TD) {
        const int id2 = id - 65536;
        const int row = id2 >> 10, col = id2 & 1023;
        split3_write(a.xt0, a.xt1, a.xt2, (size_t)id2,
                     a.x[((size_t)row * TD + (t + 1)) * HH + col]);
      }
    }
    gbar(++ep, a, wg);
  }
}

// -------- prep kernels --------
__global__ void k_tr3(const float* src, bf* d0, bf* d1, bf* d2, int R, int C) {
  __shared__ float tile[32][33];
  int c0 = blockIdx.x * 32, r0 = blockIdx.y * 32;
  int tx = threadIdx.x & 31, ty = threadIdx.x >> 5;
  for (int i = ty; i < 32; i += 8)
    tile[i][tx] = src[(size_t)(r0 + i) * C + c0 + tx];
  __syncthreads();
  for (int i = ty; i < 32; i += 8) {
    float v = tile[tx][i];
    size_t o = (size_t)(c0 + i) * R + r0 + tx;
    bf b0 = __float2bfloat16(v);
    float r1 = v - __bfloat162float(b0);
    bf b1 = __float2bfloat16(r1);
    d0[o] = b0; d1[o] = b1; d2[o] = __float2bfloat16(r1 - __bfloat162float(b1));
  }
}

__global__ void k_init(const float* h_enc, float* h_f32, bf* h0, bf* h1, bf* h2,
                       bf* i0, bf* i1, bf* i2, const float* x, bf* x0, bf* x1, bf* x2) {
  int i = blockIdx.x * blockDim.x + threadIdx.x;
  float v = h_enc[i];
  h_f32[i] = v;
  split3_write(h0, h1, h2, i, v);
  bf z = __float2bfloat16(0.f);
  i0[i] = z; i1[i] = z; i2[i] = z;
  int row = i >> 10, col = i & 1023;
  split3_write(x0, x1, x2, i, x[((size_t)row * TD + 0) * HH + col]);
}

extern "C" void kernel_launch(void* const* d_in, const int* in_sizes, int n_in,
                              void* d_out, int out_size, void* d_ws, size_t ws_size,
                              hipStream_t stream) {
  const float* x     = (const float*)d_in[0];
  const float* o_enc = (const float*)d_in[1];
  const float* h_enc = (const float*)d_in[2];
  const float* Wfeed = (const float*)d_in[3];
  const float* bfeed = (const float*)d_in[4];
  const float* Wx    = (const float*)d_in[5];
  const float* Wh    = (const float*)d_in[6];
  const float* bxi   = (const float*)d_in[7];
  const float* bhr   = (const float*)d_in[8];
  const float* Watt  = (const float*)d_in[9];
  const float* batt  = (const float*)d_in[10];

  char* w = (char*)d_ws;
  auto alloc = [&](size_t b) { char* p = w; w += (b + 255) & ~255ULL; return p; };

  const size_t M1 = (size_t)1024 * 1024 * 2;
  bf* Wf[3];  for (auto& p : Wf)  p = (bf*)alloc(M1);
  bf* Wh_[3]; for (auto& p : Wh_) p = (bf*)alloc(3 * M1);
  bf* WxF[3]; for (auto& p : WxF) p = (bf*)alloc(3 * M1);
  bf* WxX[3]; for (auto& p : WxX) p = (bf*)alloc(3 * M1);
  bf* Wa[3];  for (auto& p : Wa)  p = (bf*)alloc(2 * M1);
  float* h_f32  = (float*)alloc((size_t)2 * BB * HH * 4);
  float* gxp    = (float*)alloc((size_t)16 * BB * 1024 * 4);  // 4MB: PH2 4x64x3072 / PH4 16x64x1024
  float* gh     = (float*)alloc((size_t)BB * H3 * 4);
  float* scores = (float*)alloc((size_t)BB * TE * 4);
  const size_t AB = (size_t)BB * HH * 2;
  bf *hs[3], *ff[3], *ifd[3], *xt[3], *vl[3];
  for (auto& p : hs)  p = (bf*)alloc(AB);
  for (auto& p : ff)  p = (bf*)alloc(AB);
  for (auto& p : ifd) p = (bf*)alloc(AB);
  for (auto& p : xt)  p = (bf*)alloc(AB);
  for (auto& p : vl)  p = (bf*)alloc(AB);
  unsigned* flags = (unsigned*)alloc(8192);

  hipMemsetAsync(flags, 0, 8192, stream);
  k_tr3<<<dim3(32, 32), 256, 0, stream>>>(Wfeed, Wf[0], Wf[1], Wf[2], 1024, 1024);
  k_tr3<<<dim3(96, 32), 256, 0, stream>>>(Wx, WxF[0], WxF[1], WxF[2], 1024, 3072);
  k_tr3<<<dim3(96, 32), 256, 0, stream>>>(Wx + (size_t)1024 * 3072, WxX[0], WxX[1], WxX[2], 1024, 3072);
  k_tr3<<<dim3(96, 32), 256, 0, stream>>>(Wh, Wh_[0], Wh_[1], Wh_[2], 1024, 3072);
  k_tr3<<<dim3(32, 64), 256, 0, stream>>>(Watt, Wa[0], Wa[1], Wa[2], 2048, 1024);
  k_init<<<BB * HH / 256, 256, 0, stream>>>(h_enc, h_f32, hs[0], hs[1], hs[2],
                                            ifd[0], ifd[1], ifd[2], x, xt[0], xt[1], xt[2]);

  Args a;
  a.x = x; a.o_enc = o_enc; a.bfeed = bfeed; a.bxi = bxi; a.bhr = bhr; a.batt = batt;
  a.Wf0 = Wf[0]; a.Wf1 = Wf[1]; a.Wf2 = Wf[2];
  a.Wh0 = Wh_[0]; a.Wh1 = Wh_[1]; a.Wh2 = Wh_[2];
  a.WxF0 = WxF[0]; a.WxF1 = WxF[1]; a.WxF2 = WxF[2];
  a.WxX0 = WxX[0]; a.WxX1 = WxX[1]; a.WxX2 = WxX[2];
  a.Wa0 = Wa[0]; a.Wa1 = Wa[1]; a.Wa2 = Wa[2];
  a.h_f32 = h_f32; a.gxp = gxp; a.gh = gh; a.scores = scores;
  a.hs0 = hs[0]; a.hs1 = hs[1]; a.hs2 = hs[2];
  a.ff0 = ff[0]; a.ff1 = ff[1]; a.ff2 = ff[2];
  a.ifd0 = ifd[0]; a.ifd1 = ifd[1]; a.ifd2 = ifd[2];
  a.xt0 = xt[0]; a.xt1 = xt[1]; a.xt2 = xt[2];
  a.vl0 = vl[0]; a.vl1 = vl[1]; a.vl2 = vl[2];
  a.cnt = flags; a.cnt2 = flags + 512; a.go = flags + 544; a.afl = flags + 576;
  a.out = (float*)d_out;

  decoder_main<<<NWG, NTHR, 0, stream>>>(a);
}

// Round 7
// 33795.480 us; speedup vs baseline: 1.0320x; 1.0320x over previous
//
#include <hip/hip_runtime.h>
#include <hip/hip_bf16.h>

// Decoder: 128-step GRU + Luong attention, B=64, H=1024. Persistent kernel,
// 256 WGs x 512 thr (2 waves/SIMD), 2-level grid barrier, 5 phases/step.
// NUMERICS (frozen, bit-identical to round 5): 3-way bf16 splits + 6-pass
// MFMA; fp32 state; fp32 o_enc attention; sparse value (skip w<1e-8).
// ROUND 7: global_load_lds deep pipelines. GEMM phases: 6-frag k-blocks DMA'd
// into per-wave 2x6KB LDS rings (frag-major layout via per-lane global source
// swizzle, linear LDS dest -> conflict-free ds_read_b128), counted vmcnt(6)
// waits (never drain mid-loop). Score pass: 8-row chunks DMA'd into 2x32KB
// ring, vmcnt(4). XCD-local PH3 (b=wg&63), NO prefetch (round-6 lesson).

#define NWG 256
#define NTHR 512
constexpr int BB = 64, TD = 128, TE = 256, HH = 1024, H3 = 3072;

typedef __attribute__((ext_vector_type(8))) __bf16 bf16x8;
typedef __attribute__((ext_vector_type(4))) float f32x4;
using bf = __hip_bfloat16;

__device__ __forceinline__ f32x4 mfma16(bf16x8 a, bf16x8 b, f32x4 c) {
  return __builtin_amdgcn_mfma_f32_16x16x32_bf16(a, b, c, 0, 0, 0);
}

__device__ __forceinline__ void dma16(const void* g, void* l) {
  __builtin_amdgcn_global_load_lds(
      (const __attribute__((address_space(1))) void*)g,
      (__attribute__((address_space(3))) void*)l, 16, 0, 0);
}
__device__ __forceinline__ void wait_vm6() {
  asm volatile("s_waitcnt vmcnt(6)" ::: "memory");
  __builtin_amdgcn_sched_barrier(0);
}
__device__ __forceinline__ void wait_vm4() {
  asm volatile("s_waitcnt vmcnt(4)" ::: "memory");
  __builtin_amdgcn_sched_barrier(0);
}
__device__ __forceinline__ void wait_vm0() {
  asm volatile("s_waitcnt vmcnt(0)" ::: "memory");
  __builtin_amdgcn_sched_barrier(0);
}
__device__ __forceinline__ void wait_lgkm0() {
  asm volatile("s_waitcnt lgkmcnt(0)" ::: "memory");
  __builtin_amdgcn_sched_barrier(0);
}

struct Args {
  const float *x, *o_enc, *bfeed, *bxi, *bhr, *batt;
  const bf *Wf0, *Wf1, *Wf2, *Wh0, *Wh1, *Wh2;
  const bf *WxF0, *WxF1, *WxF2, *WxX0, *WxX1, *WxX2, *Wa0, *Wa1, *Wa2;
  float *h_f32;  // 2 planes ping-pong
  float *gxp;    // PH2 partials (2 planes 64x3072); PH4 attp (8 x 64x1024)
  float *gh, *scores;
  bf *hs0, *hs1, *hs2, *ff0, *ff1, *ff2, *ifd0, *ifd1, *ifd2;
  bf *xt0, *xt1, *xt2, *vl0, *vl1, *vl2;
  unsigned *cnt, *cnt2, *go, *afl;
  float *out;
};

__device__ __forceinline__ void gbar(unsigned ep, const Args& a, int wg) {
  __syncthreads();
  if (threadIdx.x == 0) {
    __threadfence();
    unsigned* sub = a.cnt + (wg & 15) * 32;
    unsigned o = __hip_atomic_fetch_add(sub, 1u, __ATOMIC_ACQ_REL, __HIP_MEMORY_SCOPE_AGENT);
    if (o == 15) {
      __hip_atomic_store(sub, 0u, __ATOMIC_RELAXED, __HIP_MEMORY_SCOPE_AGENT);
      unsigned o2 = __hip_atomic_fetch_add(a.cnt2, 1u, __ATOMIC_ACQ_REL, __HIP_MEMORY_SCOPE_AGENT);
      if (o2 == 15) {
        __hip_atomic_store(a.cnt2, 0u, __ATOMIC_RELAXED, __HIP_MEMORY_SCOPE_AGENT);
        __hip_atomic_store(a.go, ep, __ATOMIC_RELEASE, __HIP_MEMORY_SCOPE_AGENT);
      }
    }
    while (__hip_atomic_load(a.go, __ATOMIC_RELAXED, __HIP_MEMORY_SCOPE_AGENT) < ep)
      __builtin_amdgcn_s_sleep(2);
    __threadfence();
  }
  __syncthreads();
}

__device__ __forceinline__ void split3_write(bf* p0, bf* p1, bf* p2, size_t i, float v) {
  bf b0 = __float2bfloat16(v);
  float r1 = v - __bfloat162float(b0);
  bf b1 = __float2bfloat16(r1);
  float r2 = r1 - __bfloat162float(b1);
  p0[i] = b0; p1[i] = b1; p2[i] = __float2bfloat16(r2);
}

// DMA-pipelined 6-pass split GEMM: per k-block (K=32), 6 frags (A0,A1,A2,
// B0,B1,B2) of 1KB each land frag-major in a 2x6KB LDS ring. MFMA order is
// bit-identical to the proven gemm6 (c0..c3 accumulation).
template <int KB>
__device__ __forceinline__ f32x4 gemm6_dma(const bf* A0, const bf* A1, const bf* A2,
                                           const bf* B0, const bf* B1, const bf* B2,
                                           int sA, int sB, char* scr) {
  const int lane = threadIdx.x & 63;
  const size_t ao = (size_t)(lane & 15) * sA + (lane >> 4) * 8;
  const size_t bo = (size_t)(lane & 15) * sB + (lane >> 4) * 8;
  const bf* s0 = A0 + ao;
  const bf* s1 = A1 + ao;
  const bf* s2 = A2 + ao;
  const bf* s3 = B0 + bo;
  const bf* s4 = B1 + bo;
  const bf* s5 = B2 + bo;
  auto issue = [&](int kb, int ring) {
    char* d = scr + ring * 6144;
    dma16(s0 + kb * 32, d);
    dma16(s1 + kb * 32, d + 1024);
    dma16(s2 + kb * 32, d + 2048);
    dma16(s3 + kb * 32, d + 3072);
    dma16(s4 + kb * 32, d + 4096);
    dma16(s5 + kb * 32, d + 5120);
  };
  issue(0, 0);
  issue(1, 1);
  f32x4 c0 = {0.f, 0.f, 0.f, 0.f}, c1 = c0, c2 = c0, c3 = c0;
  const int lb = lane * 16;
  for (int kb = 0; kb < KB; ++kb) {
    if (kb + 1 < KB) wait_vm6(); else wait_vm0();
    const char* d = scr + (kb & 1) * 6144;
    bf16x8 a0 = *(const bf16x8*)(d + lb);
    bf16x8 a1 = *(const bf16x8*)(d + 1024 + lb);
    bf16x8 a2 = *(const bf16x8*)(d + 2048 + lb);
    bf16x8 b0 = *(const bf16x8*)(d + 3072 + lb);
    bf16x8 b1 = *(const bf16x8*)(d + 4096 + lb);
    bf16x8 b2 = *(const bf16x8*)(d + 5120 + lb);
    wait_lgkm0();  // frags in VGPRs before ring slot is reissued
    if (kb + 2 < KB) issue(kb + 2, kb & 1);
    c0 = mfma16(a0, b0, c0);
    c1 = mfma16(a0, b1, c1);
    c2 = mfma16(a1, b0, c2);
    c3 = mfma16(a1, b1, c3);
    c0 = mfma16(a0, b2, c0);
    c1 = mfma16(a2, b0, c1);
  }
  f32x4 s;
#pragma unroll
  for (int i = 0; i < 4; ++i) s[i] = (c0[i] + c1[i]) + (c2[i] + c3[i]);
  return s;
}

__global__ __launch_bounds__(NTHR, 2) void decoder_main(Args a) {
  const int wg = blockIdx.x;
  const int tid = threadIdx.x;
  const int lane = tid & 63;
  const int wv = tid >> 6;       // wave 0..7
  const int lrow = lane & 15;
  const int lkg = lane >> 4;

  __shared__ char s_arena[98304];        // 8 waves x 12KB GEMM rings / 2x32KB score ring
  __shared__ float s_acc[2][4][16][16];
  __shared__ float s_h[HH];
  __shared__ float s_sm[TE];
  __shared__ float s_red[8];
  __shared__ float s_val[2][256];

  unsigned ep = 0;

  for (int t = 0; t < TD; ++t) {
    // ===== PH1: ffeed (WGs 0..63) / gh (WGs 64..255); waves = (mt,kh) =====
    {
      const bool isf = (wg < 64);
      const int j0 = (isf ? wg : wg - 64) * 16;
      const bf* A0 = isf ? a.ifd0 : a.hs0;
      const bf* A1 = isf ? a.ifd1 : a.hs1;
      const bf* A2 = isf ? a.ifd2 : a.hs2;
      const bf* B0 = isf ? a.Wf0 : a.Wh0;
      const bf* B1 = isf ? a.Wf1 : a.Wh1;
      const bf* B2 = isf ? a.Wf2 : a.Wh2;
      const int mt = wv & 3, kh = wv >> 2;
      const size_t ab = (size_t)(mt * 16) * HH + kh * 512;
      const size_t bb = (size_t)j0 * HH + kh * 512;
      f32x4 acc = gemm6_dma<16>(A0 + ab, A1 + ab, A2 + ab,
                                B0 + bb, B1 + bb, B2 + bb,
                                HH, HH, s_arena + wv * 12288);
#pragma unroll
      for (int r = 0; r < 4; ++r) s_acc[kh][mt][lkg * 4 + r][lrow] = acc[r];
      __syncthreads();
#pragma unroll
      for (int e = tid; e < 1024; e += NTHR) {
        const int row = e >> 4, c = e & 15;
        const int emt = row >> 4, r2 = row & 15;
        float v = s_acc[0][emt][r2][c] + s_acc[1][emt][r2][c];
        const int col = j0 + c;
        if (isf) {
          float f = tanhf(v + a.bfeed[col]);
          split3_write(a.ff0, a.ff1, a.ff2, (size_t)row * HH + col, f);
        } else {
          a.gh[(size_t)row * H3 + col] = v + a.bhr[col];
        }
      }
    }
    gbar(++ep, a, wg);

    // ===== PH2: gx partials; 1536 wave-units (kh2, jt, g, mt), K=1024 =====
    if (wv < 6) {
      const int unit = wg * 6 + wv;
      const int kh2 = unit & 1;
      const int jt = (unit >> 1) & 63;
      const int gm = unit >> 7;
      const int g = gm >> 2, mt = gm & 3;
      const bf* A0 = kh2 ? a.xt0 : a.ff0;
      const bf* A1 = kh2 ? a.xt1 : a.ff1;
      const bf* A2 = kh2 ? a.xt2 : a.ff2;
      const bf* B0 = kh2 ? a.WxX0 : a.WxF0;
      const bf* B1 = kh2 ? a.WxX1 : a.WxF1;
      const bf* B2 = kh2 ? a.WxX2 : a.WxF2;
      const size_t ab = (size_t)(mt * 16) * HH;
      const size_t bb = (size_t)(g * HH + jt * 16) * HH;
      f32x4 acc = gemm6_dma<32>(A0 + ab, A1 + ab, A2 + ab,
                                B0 + bb, B1 + bb, B2 + bb,
                                HH, HH, s_arena + wv * 12288);
      const int gcol = g * 1024 + jt * 16 + lrow;
#pragma unroll
      for (int r = 0; r < 4; ++r)
        a.gxp[(size_t)(kh2 * 64 + mt * 16 + lkg * 4 + r) * H3 + gcol] = acc[r];
    }
    gbar(++ep, a, wg);

    // ===== PH3: GRU pointwise + scores (DMA-staged) + softmax + sparse value
    //       XCD-local: b=wg&63 -> collab WGs {b,64+b,128+b,192+b} on XCD b&7.
    {
      const int b = wg & 63, q = wg >> 6;
      const float* hold = a.h_f32 + (size_t)(t & 1) * (BB * HH);
      float* hnew = a.h_f32 + (size_t)((t + 1) & 1) * (BB * HH);
      const float* ghb = a.gh + (size_t)b * H3;
#pragma unroll
      for (int ii = 0; ii < 2; ++ii) {
        const int col = ii * NTHR + tid;
        const float* g0 = a.gxp + (size_t)b * H3;
        const float* g1 = a.gxp + (size_t)(64 + b) * H3;
        float gz = a.bxi[col] + g0[col] + g1[col];
        float gr = a.bxi[HH + col] + g0[HH + col] + g1[HH + col];
        float gc = a.bxi[2 * HH + col] + g0[2 * HH + col] + g1[2 * HH + col];
        float z = 1.f / (1.f + expf(-(gz + ghb[col])));
        float rr = 1.f / (1.f + expf(-(gr + ghb[HH + col])));
        float hc = tanhf(gc + rr * ghb[2 * HH + col]);
        float hn = z * hold[(size_t)b * HH + col] + (1.f - z) * hc;
        s_h[col] = hn;
        if (q == 0) {
          hnew[(size_t)b * HH + col] = hn;
          split3_write(a.hs0, a.hs1, a.hs2, (size_t)b * HH + col, hn);
        }
      }
      __syncthreads();
      // scores: 8 chunks of 8 rows; per chunk each wave DMA-stages its row
      // (4KB = 4 insts) into a 2x32KB ring; FMA chain identical to round 5.
      {
        f32x4 sh0 = *(const f32x4*)(s_h + 0 + lane * 4);
        f32x4 sh1 = *(const f32x4*)(s_h + 256 + lane * 4);
        f32x4 sh2 = *(const f32x4*)(s_h + 512 + lane * 4);
        f32x4 sh3 = *(const f32x4*)(s_h + 768 + lane * 4);
        const float* obase = a.o_enc + ((size_t)b * TE + q * 64) * HH;
        auto sc_issue = [&](int c, int ring) {
          const char* src = (const char*)(obase + (size_t)(c * 8 + wv) * HH) + lane * 16;
          char* d = s_arena + ring * 32768 + wv * 4096;
          dma16(src, d);
          dma16(src + 1024, d + 1024);
          dma16(src + 2048, d + 2048);
          dma16(src + 3072, d + 3072);
        };
        sc_issue(0, 0);
        for (int c = 0; c < 8; ++c) {
          if (c + 1 < 8) { sc_issue(c + 1, (c + 1) & 1); wait_vm4(); }
          else wait_vm0();
          __syncthreads();
          const float* row = (const float*)(s_arena + (c & 1) * 32768 + wv * 4096);
          f32x4 o0 = *(const f32x4*)(row + lane * 4);
          f32x4 o1 = *(const f32x4*)(row + 256 + lane * 4);
          f32x4 o2 = *(const f32x4*)(row + 512 + lane * 4);
          f32x4 o3 = *(const f32x4*)(row + 768 + lane * 4);
          float s = o0[0] * sh0[0] + o0[1] * sh0[1] + o0[2] * sh0[2] + o0[3] * sh0[3]
                  + o1[0] * sh1[0] + o1[1] * sh1[1] + o1[2] * sh1[2] + o1[3] * sh1[3]
                  + o2[0] * sh2[0] + o2[1] * sh2[1] + o2[2] * sh2[2] + o2[3] * sh2[3]
                  + o3[0] * sh3[0] + o3[1] * sh3[1] + o3[2] * sh3[2] + o3[3] * sh3[3];
          for (int off = 32; off; off >>= 1) s += __shfl_xor(s, off);
          if (lane == 0) a.scores[(size_t)b * TE + q * 64 + c * 8 + wv] = s;
          __syncthreads();
        }
      }
      if (tid == 0) {
        __threadfence();
        __hip_atomic_store(&a.afl[b * 4 + q], (unsigned)(t + 1),
                           __ATOMIC_RELEASE, __HIP_MEMORY_SCOPE_AGENT);
        for (int p = 1; p < 4; ++p) {
          unsigned idx = b * 4 + ((q + p) & 3);
          while (__hip_atomic_load(&a.afl[idx], __ATOMIC_RELAXED, __HIP_MEMORY_SCOPE_AGENT)
                 < (unsigned)(t + 1))
            __builtin_amdgcn_s_sleep(1);
        }
        __threadfence();
      }
      __syncthreads();
      // softmax over 256 (first 4 waves), tree identical to round 5
      float sc = 0.f, p = 0.f;
      if (tid < 256) {
        sc = a.scores[(size_t)b * TE + tid];
        float v = sc;
        for (int off = 32; off; off >>= 1) v = fmaxf(v, __shfl_xor(v, off));
        if (lane == 0) s_red[wv] = v;
      }
      __syncthreads();
      {
        float mx = fmaxf(fmaxf(s_red[0], s_red[1]), fmaxf(s_red[2], s_red[3]));
        if (tid < 256) {
          p = expf(sc - mx);
          float sum = p;
          for (int off = 32; off; off >>= 1) sum += __shfl_xor(sum, off);
          if (lane == 0) s_red[4 + wv] = sum;
        }
      }
      __syncthreads();
      if (tid < 256) {
        float tot = s_red[4] + s_red[5] + s_red[6] + s_red[7];
        s_sm[tid] = p / tot;
      }
      __syncthreads();
      // sparse value: identical to round 5 (L2-hot after XCD-local scores)
      {
        const int c = tid & 255, th = tid >> 8;
        const int j = q * 256 + c;
        const float* ob = a.o_enc + (size_t)b * TE * HH + j;
        float accv = 0.f;
        for (int tt2 = th * 128; tt2 < th * 128 + 128; ++tt2) {
          float w2 = s_sm[tt2];
          if (w2 > 1e-8f) accv += w2 * ob[(size_t)tt2 * HH];
        }
        s_val[th][c] = accv;
      }
      __syncthreads();
      if (tid < 256)
        split3_write(a.vl0, a.vl1, a.vl2, (size_t)b * HH + q * 256 + tid,
                     s_val[0][tid] + s_val[1][tid]);
    }
    gbar(++ep, a, wg);

    // ===== PH4: att partials; 2048 wave-units: WG=(mt,cu), wave=kq8 (K=256) =====
    {
      const int cu = wg & 63;
      const int mt = wg >> 6;
      const int kq8 = wv;
      const bool isv = (kq8 < 4);
      const int koff = (kq8 & 3) * 256;
      const bf* A0 = isv ? a.vl0 : a.hs0;
      const bf* A1 = isv ? a.vl1 : a.hs1;
      const bf* A2 = isv ? a.vl2 : a.hs2;
      const size_t ab = (size_t)(mt * 16) * HH + koff;
      const size_t bb = (size_t)(cu * 16) * 2048 + kq8 * 256;
      f32x4 acc = gemm6_dma<8>(A0 + ab, A1 + ab, A2 + ab,
                               a.Wa0 + bb, a.Wa1 + bb, a.Wa2 + bb,
                               HH, 2048, s_arena + wv * 12288);
#pragma unroll
      for (int r = 0; r < 4; ++r)
        a.gxp[(size_t)(kq8 * 64 + mt * 16 + lkg * 4 + r) * 1024 + cu * 16 + lrow] = acc[r];
    }
    gbar(++ep, a, wg);

    // ===== PH5: att reduce + tanh -> out/ifd; spare threads stage x_{t+1} =====
    {
      const int id = wg * NTHR + tid;  // 0..131071
      if (id < 65536) {
        const int row = id >> 10, col = id & 1023;
        float s = a.batt[col];
#pragma unroll
        for (int kq = 0; kq < 8; ++kq) s += a.gxp[(size_t)(kq * 64 + row) * 1024 + col];
        float hv = tanhf(s);
        a.out[((size_t)row * TD + t) * HH + col] = hv;
        split3_write(a.ifd0, a.ifd1, a.ifd2, (size_t)row * HH + col, hv);
      } else if (t + 1 < TD) {
        const int id2 = id - 65536;
        const int row = id2 >> 10, col = id2 & 1023;
        split3_write(a.xt0, a.xt1, a.xt2, (size_t)id2,
                     a.x[((size_t)row * TD + (t + 1)) * HH + col]);
      }
    }
    gbar(++ep, a, wg);
  }
}

// -------- prep kernels --------
__global__ void k_tr3(const float* src, bf* d0, bf* d1, bf* d2, int R, int C) {
  __shared__ float tile[32][33];
  int c0 = blockIdx.x * 32, r0 = blockIdx.y * 32;
  int tx = threadIdx.x & 31, ty = threadIdx.x >> 5;
  for (int i = ty; i < 32; i += 8)
    tile[i][tx] = src[(size_t)(r0 + i) * C + c0 + tx];
  __syncthreads();
  for (int i = ty; i < 32; i += 8) {
    float v = tile[tx][i];
    size_t o = (size_t)(c0 + i) * R + r0 + tx;
    bf b0 = __float2bfloat16(v);
    float r1 = v - __bfloat162float(b0);
    bf b1 = __float2bfloat16(r1);
    d0[o] = b0; d1[o] = b1; d2[o] = __float2bfloat16(r1 - __bfloat162float(b1));
  }
}

__global__ void k_init(const float* h_enc, float* h_f32, bf* h0, bf* h1, bf* h2,
                       bf* i0, bf* i1, bf* i2, const float* x, bf* x0, bf* x1, bf* x2) {
  int i = blockIdx.x * blockDim.x + threadIdx.x;
  float v = h_enc[i];
  h_f32[i] = v;
  split3_write(h0, h1, h2, i, v);
  bf z = __float2bfloat16(0.f);
  i0[i] = z; i1[i] = z; i2[i] = z;
  int row = i >> 10, col = i & 1023;
  split3_write(x0, x1, x2, i, x[((size_t)row * TD + 0) * HH + col]);
}

extern "C" void kernel_launch(void* const* d_in, const int* in_sizes, int n_in,
                              void* d_out, int out_size, void* d_ws, size_t ws_size,
                              hipStream_t stream) {
  const float* x     = (const float*)d_in[0];
  const float* o_enc = (const float*)d_in[1];
  const float* h_enc = (const float*)d_in[2];
  const float* Wfeed = (const float*)d_in[3];
  const float* bfeed = (const float*)d_in[4];
  const float* Wx    = (const float*)d_in[5];
  const float* Wh    = (const float*)d_in[6];
  const float* bxi   = (const float*)d_in[7];
  const float* bhr   = (const float*)d_in[8];
  const float* Watt  = (const float*)d_in[9];
  const float* batt  = (const float*)d_in[10];

  char* w = (char*)d_ws;
  auto alloc = [&](size_t b) { char* p = w; w += (b + 255) & ~255ULL; return p; };

  const size_t M1 = (size_t)1024 * 1024 * 2;
  bf* Wf[3];  for (auto& p : Wf)  p = (bf*)alloc(M1);
  bf* Wh_[3]; for (auto& p : Wh_) p = (bf*)alloc(3 * M1);
  bf* WxF[3]; for (auto& p : WxF) p = (bf*)alloc(3 * M1);
  bf* WxX[3]; for (auto& p : WxX) p = (bf*)alloc(3 * M1);
  bf* Wa[3];  for (auto& p : Wa)  p = (bf*)alloc(2 * M1);
  float* h_f32  = (float*)alloc((size_t)2 * BB * HH * 4);
  float* gxp    = (float*)alloc((size_t)8 * BB * 1024 * 4);
  float* gh     = (float*)alloc((size_t)BB * H3 * 4);
  float* scores = (float*)alloc((size_t)BB * TE * 4);
  const size_t AB = (size_t)BB * HH * 2;
  bf *hs[3], *ff[3], *ifd[3], *xt[3], *vl[3];
  for (auto& p : hs)  p = (bf*)alloc(AB);
  for (auto& p : ff)  p = (bf*)alloc(AB);
  for (auto& p : ifd) p = (bf*)alloc(AB);
  for (auto& p : xt)  p = (bf*)alloc(AB);
  for (auto& p : vl)  p = (bf*)alloc(AB);
  unsigned* flags = (unsigned*)alloc(8192);

  hipMemsetAsync(flags, 0, 8192, stream);
  k_tr3<<<dim3(32, 32), 256, 0, stream>>>(Wfeed, Wf[0], Wf[1], Wf[2], 1024, 1024);
  k_tr3<<<dim3(96, 32), 256, 0, stream>>>(Wx, WxF[0], WxF[1], WxF[2], 1024, 3072);
  k_tr3<<<dim3(96, 32), 256, 0, stream>>>(Wx + (size_t)1024 * 3072, WxX[0], WxX[1], WxX[2], 1024, 3072);
  k_tr3<<<dim3(96, 32), 256, 0, stream>>>(Wh, Wh_[0], Wh_[1], Wh_[2], 1024, 3072);
  k_tr3<<<dim3(32, 64), 256, 0, stream>>>(Watt, Wa[0], Wa[1], Wa[2], 2048, 1024);
  k_init<<<BB * HH / 256, 256, 0, stream>>>(h_enc, h_f32, hs[0], hs[1], hs[2],
                                            ifd[0], ifd[1], ifd[2], x, xt[0], xt[1], xt[2]);

  Args a;
  a.x = x; a.o_enc = o_enc; a.bfeed = bfeed; a.bxi = bxi; a.bhr = bhr; a.batt = batt;
  a.Wf0 = Wf[0]; a.Wf1 = Wf[1]; a.Wf2 = Wf[2];
  a.Wh0 = Wh_[0]; a.Wh1 = Wh_[1]; a.Wh2 = Wh_[2];
  a.WxF0 = WxF[0]; a.WxF1 = WxF[1]; a.WxF2 = WxF[2];
  a.WxX0 = WxX[0]; a.WxX1 = WxX[1]; a.WxX2 = WxX[2];
  a.Wa0 = Wa[0]; a.Wa1 = Wa[1]; a.Wa2 = Wa[2];
  a.h_f32 = h_f32; a.gxp = gxp; a.gh = gh; a.scores = scores;
  a.hs0 = hs[0]; a.hs1 = hs[1]; a.hs2 = hs[2];
  a.ff0 = ff[0]; a.ff1 = ff[1]; a.ff2 = ff[2];
  a.ifd0 = ifd[0]; a.ifd1 = ifd[1]; a.ifd2 = ifd[2];
  a.xt0 = xt[0]; a.xt1 = xt[1]; a.xt2 = xt[2];
  a.vl0 = vl[0]; a.vl1 = vl[1]; a.vl2 = vl[2];
  a.cnt = flags; a.cnt2 = flags + 512; a.go = flags + 544; a.afl = flags + 576;
  a.out = (float*)d_out;

  decoder_main<<<NWG, NTHR, 0, stream>>>(a);
}

// Round 10
// 23375.858 us; speedup vs baseline: 1.4920x; 1.4457x over previous
//
#include <hip/hip_runtime.h>
#include <hip/hip_bf16.h>

// Decoder: 128-step GRU + Luong attention, B=64, H=1024. Persistent kernel,
// 256 WGs x 1024 thr (16 waves/CU), 2-level grid barrier, 4 phases/step.
// NUMERICS (frozen, proven absmax 0.0078-0.0117): bf16 3-way splits + 6-pass
// MFMA (rep err 2^-27); fp32 state; fp32 o_enc scores+value; sparse value.
// ROUND 10 = ROUND 9 resubmit (round-9 bench died in infra push phase; kernel
// never ran). 1024-thr (measured 875 GB/s rate at 16 waves/CU); within-WG
// K-reduce for PH2/PH4 (kills gxp/attp traffic, 4 barriers/step);
// deterministic ballot-compacted sparse value (dense loads -> MLP restored).
// No prefetch (r6 lesson: self-evicting), no DMA (r7 lesson: loses L2 hits).

#define NWG 256
#define NTHR 1024
constexpr int BB = 64, TD = 128, TE = 256, HH = 1024, H3 = 3072;

typedef __attribute__((ext_vector_type(8))) __bf16 bf16x8;
typedef __attribute__((ext_vector_type(4))) float f32x4;
using bf = __hip_bfloat16;

__device__ __forceinline__ f32x4 mfma16(bf16x8 a, bf16x8 b, f32x4 c) {
  return __builtin_amdgcn_mfma_f32_16x16x32_bf16(a, b, c, 0, 0, 0);
}

struct Args {
  const float *x, *o_enc, *bfeed, *bxi, *bhr, *batt;
  const bf *Wf0, *Wf1, *Wf2, *Wh0, *Wh1, *Wh2;
  const bf *WxF0, *WxF1, *WxF2, *WxX0, *WxX1, *WxX2, *Wa0, *Wa1, *Wa2;
  float *h_f32;          // 2 planes ping-pong
  float *gx;             // 64 x 3072 (complete, single plane)
  float *gh, *scores;
  bf *hs0, *hs1, *hs2, *ff0, *ff1, *ff2, *ifd0, *ifd1, *ifd2;
  bf *xt0, *xt1, *xt2, *vl0, *vl1, *vl2;
  unsigned *cnt, *cnt2, *go, *afl;
  float *out;
};

__device__ __forceinline__ void gbar(unsigned ep, const Args& a, int wg) {
  __syncthreads();
  if (threadIdx.x == 0) {
    __threadfence();
    unsigned* sub = a.cnt + (wg & 15) * 32;
    unsigned o = __hip_atomic_fetch_add(sub, 1u, __ATOMIC_ACQ_REL, __HIP_MEMORY_SCOPE_AGENT);
    if (o == 15) {
      __hip_atomic_store(sub, 0u, __ATOMIC_RELAXED, __HIP_MEMORY_SCOPE_AGENT);
      unsigned o2 = __hip_atomic_fetch_add(a.cnt2, 1u, __ATOMIC_ACQ_REL, __HIP_MEMORY_SCOPE_AGENT);
      if (o2 == 15) {
        __hip_atomic_store(a.cnt2, 0u, __ATOMIC_RELAXED, __HIP_MEMORY_SCOPE_AGENT);
        __hip_atomic_store(a.go, ep, __ATOMIC_RELEASE, __HIP_MEMORY_SCOPE_AGENT);
      }
    }
    while (__hip_atomic_load(a.go, __ATOMIC_RELAXED, __HIP_MEMORY_SCOPE_AGENT) < ep)
      __builtin_amdgcn_s_sleep(2);
    __threadfence();
  }
  __syncthreads();
}

__device__ __forceinline__ void split3_write(bf* p0, bf* p1, bf* p2, size_t i, float v) {
  bf b0 = __float2bfloat16(v);
  float r1 = v - __bfloat162float(b0);
  bf b1 = __float2bfloat16(r1);
  float r2 = r1 - __bfloat162float(b1);
  p0[i] = b0; p1[i] = b1; p2[i] = __float2bfloat16(r2);
}

template <int K>
__device__ __forceinline__ f32x4 gemm6(const bf* A0, const bf* A1, const bf* A2,
                                       const bf* B0, const bf* B1, const bf* B2) {
  f32x4 c0 = {0.f, 0.f, 0.f, 0.f}, c1 = c0, c2 = c0, c3 = c0;
#pragma unroll 4
  for (int k = 0; k < K; k += 32) {
    bf16x8 a0 = *(const bf16x8*)(A0 + k);
    bf16x8 a1 = *(const bf16x8*)(A1 + k);
    bf16x8 a2 = *(const bf16x8*)(A2 + k);
    bf16x8 b0 = *(const bf16x8*)(B0 + k);
    bf16x8 b1 = *(const bf16x8*)(B1 + k);
    bf16x8 b2 = *(const bf16x8*)(B2 + k);
    c0 = mfma16(a0, b0, c0);
    c1 = mfma16(a0, b1, c1);
    c2 = mfma16(a1, b0, c2);
    c3 = mfma16(a1, b1, c3);
    c0 = mfma16(a0, b2, c0);
    c1 = mfma16(a2, b0, c1);
  }
  f32x4 s;
#pragma unroll
  for (int i = 0; i < 4; ++i) s[i] = (c0[i] + c1[i]) + (c2[i] + c3[i]);
  return s;
}

__global__ __launch_bounds__(NTHR, 4) void decoder_main(Args a) {
  const int wg = blockIdx.x;
  const int tid = threadIdx.x;
  const int lane = tid & 63;
  const int wv = tid >> 6;       // wave 0..15
  const int lrow = lane & 15;
  const int lkg = lane >> 4;

  __shared__ float s_u[4096];    // 16KB union: PH1 [kq][mt][256], PH2 [ci][ku][256], PH4 [kq16][256]
  __shared__ float s_h[HH];
  __shared__ float s_sm[TE];
  __shared__ float s_red[8];
  __shared__ float s_val[2][256];
  __shared__ int s_idx[TE];
  __shared__ int s_wcnt[4];

  unsigned ep = 0;

  for (int t = 0; t < TD; ++t) {
    // ===== PH1: ffeed (WGs 0..63) / gh (WGs 64..255); waves = (mt, kq) =====
    {
      const bool isf = (wg < 64);
      const int j0 = (isf ? wg : wg - 64) * 16;
      const bf* A0 = isf ? a.ifd0 : a.hs0;
      const bf* A1 = isf ? a.ifd1 : a.hs1;
      const bf* A2 = isf ? a.ifd2 : a.hs2;
      const bf* B0 = isf ? a.Wf0 : a.Wh0;
      const bf* B1 = isf ? a.Wf1 : a.Wh1;
      const bf* B2 = isf ? a.Wf2 : a.Wh2;
      const int mt = wv >> 2, kq = wv & 3;
      const size_t aoff = (size_t)(mt * 16 + lrow) * HH + kq * 256 + lkg * 8;
      const size_t boff = (size_t)(j0 + lrow) * HH + kq * 256 + lkg * 8;
      f32x4 acc = gemm6<256>(A0 + aoff, A1 + aoff, A2 + aoff, B0 + boff, B1 + boff, B2 + boff);
#pragma unroll
      for (int r = 0; r < 4; ++r) s_u[kq * 1024 + mt * 256 + (lkg * 4 + r) * 16 + lrow] = acc[r];
      __syncthreads();
      {
        const int row = tid >> 4, c = tid & 15;  // 1024 outputs, one per thread
        const int emt = row >> 4, r2 = row & 15;
        const int e = emt * 256 + r2 * 16 + c;
        float v = (s_u[e] + s_u[1024 + e]) + (s_u[2048 + e] + s_u[3072 + e]);
        const int col = j0 + c;
        if (isf) {
          float f = tanhf(v + a.bfeed[col]);
          split3_write(a.ff0, a.ff1, a.ff2, (size_t)row * HH + col, f);
        } else {
          a.gh[(size_t)row * H3 + col] = v + a.bhr[col];
        }
      }
    }
    gbar(++ep, a, wg);

    // ===== PH2: gx complete; WG=(jt,sub); 12 waves = (ci 0..2, ku 0..3) =====
    {
      const int jt = wg >> 2, sub = wg & 3;
      if (wv < 12) {
        const int ci = wv >> 2, ku = wv & 3;
        const int c2 = sub * 3 + ci;          // tile 0..11
        const int g = c2 >> 2, mt = c2 & 3;
        const int op = ku >> 1, kh = ku & 1;  // op 0: ff@WxF, 1: xt@WxX; kh: K-half
        const bf* A0 = op ? a.xt0 : a.ff0;
        const bf* A1 = op ? a.xt1 : a.ff1;
        const bf* A2 = op ? a.xt2 : a.ff2;
        const bf* B0 = op ? a.WxX0 : a.WxF0;
        const bf* B1 = op ? a.WxX1 : a.WxF1;
        const bf* B2 = op ? a.WxX2 : a.WxF2;
        const size_t aoff = (size_t)(mt * 16 + lrow) * HH + kh * 512 + lkg * 8;
        const size_t boff = (size_t)(g * HH + jt * 16 + lrow) * HH + kh * 512 + lkg * 8;
        f32x4 acc = gemm6<512>(A0 + aoff, A1 + aoff, A2 + aoff, B0 + boff, B1 + boff, B2 + boff);
#pragma unroll
        for (int r = 0; r < 4; ++r)
          s_u[ci * 1024 + ku * 256 + (lkg * 4 + r) * 16 + lrow] = acc[r];
      }
      __syncthreads();
      if (tid < 768) {
        const int ci2 = tid >> 8, e = tid & 255;
        const int r16 = e >> 4, c16 = e & 15;
        const int base = ci2 * 1024 + e;
        float v = (s_u[base] + s_u[base + 256]) + (s_u[base + 512] + s_u[base + 768]);
        const int c2 = sub * 3 + ci2;
        const int g = c2 >> 2, mt = c2 & 3;
        a.gx[(size_t)(mt * 16 + r16) * H3 + g * 1024 + jt * 16 + c16] = v;
      }
    }
    gbar(++ep, a, wg);

    // ===== PH3: GRU pointwise + scores + softmax + compacted sparse value =====
    {
      const int b = wg >> 2, q = wg & 3;   // round-5 mapping (FETCH-proven)
      const float* hold = a.h_f32 + (size_t)(t & 1) * (BB * HH);
      float* hnew = a.h_f32 + (size_t)((t + 1) & 1) * (BB * HH);
      const float* ghb = a.gh + (size_t)b * H3;
      {
        const int col = tid;  // 1024 cols, one per thread
        const float* gxb = a.gx + (size_t)b * H3;
        float gz = a.bxi[col] + gxb[col];
        float gr = a.bxi[HH + col] + gxb[HH + col];
        float gc = a.bxi[2 * HH + col] + gxb[2 * HH + col];
        float z = 1.f / (1.f + expf(-(gz + ghb[col])));
        float rr = 1.f / (1.f + expf(-(gr + ghb[HH + col])));
        float hc = tanhf(gc + rr * ghb[2 * HH + col]);
        float hn = z * hold[(size_t)b * HH + col] + (1.f - z) * hc;
        s_h[col] = hn;
        if (q == 0) {
          hnew[(size_t)b * HH + col] = hn;
          split3_write(a.hs0, a.hs1, a.hs2, (size_t)b * HH + col, hn);
        }
      }
      __syncthreads();
      // scores: 16 waves x 4 rows, coalesced 1KB loads, 2-deep pipelined
      {
        f32x4 sh0 = *(const f32x4*)(s_h + 0 + lane * 4);
        f32x4 sh1 = *(const f32x4*)(s_h + 256 + lane * 4);
        f32x4 sh2 = *(const f32x4*)(s_h + 512 + lane * 4);
        f32x4 sh3 = *(const f32x4*)(s_h + 768 + lane * 4);
        const float* obase = a.o_enc + ((size_t)b * TE + q * 64 + wv * 4) * HH + lane * 4;
        f32x4 o0 = *(const f32x4*)(obase);
        f32x4 o1 = *(const f32x4*)(obase + 256);
        f32x4 o2 = *(const f32x4*)(obase + 512);
        f32x4 o3 = *(const f32x4*)(obase + 768);
#pragma unroll
        for (int i = 0; i < 4; ++i) {
          f32x4 n0, n1, n2, n3;
          if (i + 1 < 4) {
            const float* nr = obase + (size_t)(i + 1) * HH;
            n0 = *(const f32x4*)(nr);
            n1 = *(const f32x4*)(nr + 256);
            n2 = *(const f32x4*)(nr + 512);
            n3 = *(const f32x4*)(nr + 768);
          }
          float s = o0[0] * sh0[0] + o0[1] * sh0[1] + o0[2] * sh0[2] + o0[3] * sh0[3]
                  + o1[0] * sh1[0] + o1[1] * sh1[1] + o1[2] * sh1[2] + o1[3] * sh1[3]
                  + o2[0] * sh2[0] + o2[1] * sh2[1] + o2[2] * sh2[2] + o2[3] * sh2[3]
                  + o3[0] * sh3[0] + o3[1] * sh3[1] + o3[2] * sh3[2] + o3[3] * sh3[3];
          for (int off = 32; off; off >>= 1) s += __shfl_xor(s, off);
          if (lane == 0) a.scores[(size_t)b * TE + q * 64 + wv * 4 + i] = s;
          o0 = n0; o1 = n1; o2 = n2; o3 = n3;
        }
      }
      __syncthreads();
      if (tid == 0) {
        __threadfence();
        __hip_atomic_store(&a.afl[b * 4 + q], (unsigned)(t + 1),
                           __ATOMIC_RELEASE, __HIP_MEMORY_SCOPE_AGENT);
        for (int p = 1; p < 4; ++p) {
          unsigned idx = b * 4 + ((q + p) & 3);
          while (__hip_atomic_load(&a.afl[idx], __ATOMIC_RELAXED, __HIP_MEMORY_SCOPE_AGENT)
                 < (unsigned)(t + 1))
            __builtin_amdgcn_s_sleep(1);
        }
        __threadfence();
      }
      __syncthreads();
      // softmax over 256 (first 4 waves)
      float sc = 0.f, p = 0.f;
      if (tid < 256) {
        sc = a.scores[(size_t)b * TE + tid];
        float v = sc;
        for (int off = 32; off; off >>= 1) v = fmaxf(v, __shfl_xor(v, off));
        if (lane == 0) s_red[wv] = v;
      }
      __syncthreads();
      {
        float mx = fmaxf(fmaxf(s_red[0], s_red[1]), fmaxf(s_red[2], s_red[3]));
        if (tid < 256) {
          p = expf(sc - mx);
          float sum = p;
          for (int off = 32; off; off >>= 1) sum += __shfl_xor(sum, off);
          if (lane == 0) s_red[4 + wv] = sum;
        }
      }
      __syncthreads();
      bool act = false;
      unsigned long long bm = 0;
      if (tid < 256) {
        float tot = s_red[4] + s_red[5] + s_red[6] + s_red[7];
        float w2 = p / tot;
        s_sm[tid] = w2;
        act = (w2 > 1e-8f);
        bm = __ballot(act);
        if (lane == 0) s_wcnt[wv] = __popcll(bm);
      }
      __syncthreads();
      // ordered (deterministic) compaction of active indices
      if (tid < 256 && act) {
        int base = 0;
        for (int w2i = 0; w2i < wv; ++w2i) base += s_wcnt[w2i];
        int pos = base + __popcll(bm & ((1ULL << lane) - 1));
        s_idx[pos] = tid;
      }
      __syncthreads();
      const int nact = s_wcnt[0] + s_wcnt[1] + s_wcnt[2] + s_wcnt[3];
      // dense value loop over compacted list (unconditional loads -> MLP)
      if (tid < 512) {
        const int c = tid & 255, th = tid >> 8;
        const int j = q * 256 + c;
        const float* ob = a.o_enc + (size_t)b * TE * HH + j;
        float accv = 0.f;
        for (int ii = th; ii < nact; ii += 2) {
          const int tt2 = s_idx[ii];
          accv += s_sm[tt2] * ob[(size_t)tt2 * HH];
        }
        s_val[th][c] = accv;
      }
      __syncthreads();
      if (tid < 256)
        split3_write(a.vl0, a.vl1, a.vl2, (size_t)b * HH + q * 256 + tid,
                     s_val[0][tid] + s_val[1][tid]);
    }
    gbar(++ep, a, wg);

    // ===== PH4: att GEMM, full K in-WG; WG=(mt,cu), wave=kq16 (K=128);
    //            LDS reduce -> tanh -> out/ifd direct. Also stage x_{t+1}. =====
    {
      const int cu = wg & 63;
      const int mt = wg >> 6;
      const int kq16 = wv;
      const bool isv = (kq16 < 8);
      const int koff = (kq16 & 7) * 128;
      const bf* A0 = isv ? a.vl0 : a.hs0;
      const bf* A1 = isv ? a.vl1 : a.hs1;
      const bf* A2 = isv ? a.vl2 : a.hs2;
      const size_t aoff = (size_t)(mt * 16 + lrow) * HH + koff + lkg * 8;
      const size_t boff = (size_t)(cu * 16 + lrow) * 2048 + kq16 * 128 + lkg * 8;
      f32x4 acc = gemm6<128>(A0 + aoff, A1 + aoff, A2 + aoff,
                             a.Wa0 + boff, a.Wa1 + boff, a.Wa2 + boff);
#pragma unroll
      for (int r = 0; r < 4; ++r)
        s_u[kq16 * 256 + (lkg * 4 + r) * 16 + lrow] = acc[r];
      __syncthreads();
      if (tid < 256) {
        const int r16 = tid >> 4, c16 = tid & 15;
        const int e = r16 * 16 + c16;
        float v = a.batt[cu * 16 + c16];
#pragma unroll
        for (int kq = 0; kq < 16; ++kq) v += s_u[kq * 256 + e];
        float hv = tanhf(v);
        const int row = mt * 16 + r16;
        const int col = cu * 16 + c16;
        a.out[((size_t)row * TD + t) * HH + col] = hv;
        split3_write(a.ifd0, a.ifd1, a.ifd2, (size_t)row * HH + col, hv);
      }
      // stage x_{t+1}: WGs 0..63, one batch-row each, 1024 cols = 1024 threads
      if (wg < 64 && t + 1 < TD) {
        split3_write(a.xt0, a.xt1, a.xt2, (size_t)wg * HH + tid,
                     a.x[((size_t)wg * TD + (t + 1)) * HH + tid]);
      }
    }
    gbar(++ep, a, wg);
  }
}

// -------- prep kernels --------
__global__ void k_tr3(const float* src, bf* d0, bf* d1, bf* d2, int R, int C) {
  __shared__ float tile[32][33];
  int c0 = blockIdx.x * 32, r0 = blockIdx.y * 32;
  int tx = threadIdx.x & 31, ty = threadIdx.x >> 5;
  for (int i = ty; i < 32; i += 8)
    tile[i][tx] = src[(size_t)(r0 + i) * C + c0 + tx];
  __syncthreads();
  for (int i = ty; i < 32; i += 8) {
    float v = tile[tx][i];
    size_t o = (size_t)(c0 + i) * R + r0 + tx;
    bf b0 = __float2bfloat16(v);
    float r1 = v - __bfloat162float(b0);
    bf b1 = __float2bfloat16(r1);
    d0[o] = b0; d1[o] = b1; d2[o] = __float2bfloat16(r1 - __bfloat162float(b1));
  }
}

__global__ void k_init(const float* h_enc, float* h_f32, bf* h0, bf* h1, bf* h2,
                       bf* i0, bf* i1, bf* i2, const float* x, bf* x0, bf* x1, bf* x2) {
  int i = blockIdx.x * blockDim.x + threadIdx.x;
  float v = h_enc[i];
  h_f32[i] = v;
  split3_write(h0, h1, h2, i, v);
  bf z = __float2bfloat16(0.f);
  i0[i] = z; i1[i] = z; i2[i] = z;
  int row = i >> 10, col = i & 1023;
  split3_write(x0, x1, x2, i, x[((size_t)row * TD + 0) * HH + col]);
}

extern "C" void kernel_launch(void* const* d_in, const int* in_sizes, int n_in,
                              void* d_out, int out_size, void* d_ws, size_t ws_size,
                              hipStream_t stream) {
  const float* x     = (const float*)d_in[0];
  const float* o_enc = (const float*)d_in[1];
  const float* h_enc = (const float*)d_in[2];
  const float* Wfeed = (const float*)d_in[3];
  const float* bfeed = (const float*)d_in[4];
  const float* Wx    = (const float*)d_in[5];
  const float* Wh    = (const float*)d_in[6];
  const float* bxi   = (const float*)d_in[7];
  const float* bhr   = (const float*)d_in[8];
  const float* Watt  = (const float*)d_in[9];
  const float* batt  = (const float*)d_in[10];

  char* w = (char*)d_ws;
  auto alloc = [&](size_t b) { char* p = w; w += (b + 255) & ~255ULL; return p; };

  const size_t M1 = (size_t)1024 * 1024 * 2;
  bf* Wf[3];  for (auto& p : Wf)  p = (bf*)alloc(M1);
  bf* Wh_[3]; for (auto& p : Wh_) p = (bf*)alloc(3 * M1);
  bf* WxF[3]; for (auto& p : WxF) p = (bf*)alloc(3 * M1);
  bf* WxX[3]; for (auto& p : WxX) p = (bf*)alloc(3 * M1);
  bf* Wa[3];  for (auto& p : Wa)  p = (bf*)alloc(2 * M1);
  float* h_f32  = (float*)alloc((size_t)2 * BB * HH * 4);
  float* gx     = (float*)alloc((size_t)BB * H3 * 4);
  float* gh     = (float*)alloc((size_t)BB * H3 * 4);
  float* scores = (float*)alloc((size_t)BB * TE * 4);
  const size_t AB = (size_t)BB * HH * 2;
  bf *hs[3], *ff[3], *ifd[3], *xt[3], *vl[3];
  for (auto& p : hs)  p = (bf*)alloc(AB);
  for (auto& p : ff)  p = (bf*)alloc(AB);
  for (auto& p : ifd) p = (bf*)alloc(AB);
  for (auto& p : xt)  p = (bf*)alloc(AB);
  for (auto& p : vl)  p = (bf*)alloc(AB);
  unsigned* flags = (unsigned*)alloc(8192);

  hipMemsetAsync(flags, 0, 8192, stream);
  k_tr3<<<dim3(32, 32), 256, 0, stream>>>(Wfeed, Wf[0], Wf[1], Wf[2], 1024, 1024);
  k_tr3<<<dim3(96, 32), 256, 0, stream>>>(Wx, WxF[0], WxF[1], WxF[2], 1024, 3072);
  k_tr3<<<dim3(96, 32), 256, 0, stream>>>(Wx + (size_t)1024 * 3072, WxX[0], WxX[1], WxX[2], 1024, 3072);
  k_tr3<<<dim3(96, 32), 256, 0, stream>>>(Wh, Wh_[0], Wh_[1], Wh_[2], 1024, 3072);
  k_tr3<<<dim3(32, 64), 256, 0, stream>>>(Watt, Wa[0], Wa[1], Wa[2], 2048, 1024);
  k_init<<<BB * HH / 256, 256, 0, stream>>>(h_enc, h_f32, hs[0], hs[1], hs[2],
                                            ifd[0], ifd[1], ifd[2], x, xt[0], xt[1], xt[2]);

  Args a;
  a.x = x; a.o_enc = o_enc; a.bfeed = bfeed; a.bxi = bxi; a.bhr = bhr; a.batt = batt;
  a.Wf0 = Wf[0]; a.Wf1 = Wf[1]; a.Wf2 = Wf[2];
  a.Wh0 = Wh_[0]; a.Wh1 = Wh_[1]; a.Wh2 = Wh_[2];
  a.WxF0 = WxF[0]; a.WxF1 = WxF[1]; a.WxF2 = WxF[2];
  a.WxX0 = WxX[0]; a.WxX1 = WxX[1]; a.WxX2 = WxX[2];
  a.Wa0 = Wa[0]; a.Wa1 = Wa[1]; a.Wa2 = Wa[2];
  a.h_f32 = h_f32; a.gx = gx; a.gh = gh; a.scores = scores;
  a.hs0 = hs[0]; a.hs1 = hs[1]; a.hs2 = hs[2];
  a.ff0 = ff[0]; a.ff1 = ff[1]; a.ff2 = ff[2];
  a.ifd0 = ifd[0]; a.ifd1 = ifd[1]; a.ifd2 = ifd[2];
  a.xt0 = xt[0]; a.xt1 = xt[1]; a.xt2 = xt[2];
  a.vl0 = vl[0]; a.vl1 = vl[1]; a.vl2 = vl[2];
  a.cnt = flags; a.cnt2 = flags + 512; a.go = flags + 544; a.afl = flags + 576;
  a.out = (float*)d_out;

  decoder_main<<<NWG, NTHR, 0, stream>>>(a);
}